// Round 15
// baseline (239.957 us; speedup 1.0000x reference)
//
#include <hip/hip_runtime.h>
#include <hip/hip_bf16.h>
#include <math.h>

#define LEVELS 17
#define VARN   4
#define UNITS  51
#define MOTOR  17
#define NB     32768
#define TT     (NB + 4)      // 32772
#define DD     68
#define LOG2E  1.4426950408889634f
#define TROWS  16

// scan geometry
#define W_WARM  10
#define L_CHUNK 40
#define NCHUNK  ((TT + L_CHUNK - 1) / L_CHUNK)   // 820 blocks (4 waves each)

// fallback geometry
#define W_F     64
#define L_F     64
#define NCHUNK_F ((TT + L_F - 1) / L_F)
#define CAP_R  16

// MFMA MLP geometry
#define MROWS  48
#define MBLK   ((TT + MROWS - 1) / MROWS)
#define EBLK   ((NB + MROWS - 1) / MROWS)
#define BUFSZ  (48 * 272 + 64)
#define EBUFSZ (48 * 72 + 64)

// weight table offsets (shorts), fragment-packed layout (round-11 proven)
#define OFF_WA 0
#define OFF_WB 7680
#define OFF_WC 24576
#define OFF_WD 76800
#define OFF_WE 155136
#define OFF_WF 205824
#define OFF_P1 221184
#define OFF_P2 228864
#define WTS_SHORTS 236544
#define PSENS_N (VARN * LEVELS * UNITS)          // 3468 float4 = 55 KB

typedef __attribute__((ext_vector_type(8))) short short8v;
typedef __attribute__((ext_vector_type(4))) float f32x4;

__device__ __forceinline__ float fast_rcp(float x) { return __builtin_amdgcn_rcpf(x); }
__device__ __forceinline__ float fast_exp2(float x) { return __builtin_amdgcn_exp2f(x); }
__device__ __forceinline__ float sigf(float x) { return fast_rcp(1.0f + __expf(-x)); }
__device__ __forceinline__ float softplusf(float x) { return logf(1.0f + expf(x)); }
__device__ __forceinline__ unsigned short f2bf(float x) {
    unsigned int u = __float_as_uint(x);
    unsigned int r = u + 0x7FFFu + ((u >> 16) & 1u);
    return (unsigned short)(r >> 16);
}

// ---------------------------------------------------------------------------
// prep_all: fragment-packed weights (ph 0..7) + folded sensory table (ph 8).
// ---------------------------------------------------------------------------
__global__ __launch_bounds__(256) void prep_all(
    const float* __restrict__ tW1, const float* __restrict__ tW2, const float* __restrict__ tW3,
    const float* __restrict__ gW1, const float* __restrict__ gW2, const float* __restrict__ gW3,
    const float* __restrict__ pW1, const float* __restrict__ pW2,
    const float* __restrict__ sens_w, const float* __restrict__ sens_sigma,
    const float* __restrict__ sens_mu, const float* __restrict__ sens_erev,
    unsigned short* __restrict__ wts, float4* __restrict__ psens)
{
    const int ph = blockIdx.y;
    if (ph == 8) {
        int idx = blockIdx.x * 256 + threadIdx.x;
        if (idx >= PSENS_N) return;
        float sg = sens_sigma[idx], m = sens_mu[idx];
        float wf = softplusf(sens_w[idx]);
        psens[idx] = make_float4(fast_exp2(sg * m * LOG2E), -sg * LOG2E, wf, wf * sens_erev[idx]);
        return;
    }
    const int KTt[8]   = {3, 3, 6, 9, 9, 6, 3, 3};
    const int NCt[8]   = {5, 11, 17, 17, 11, 5, 5, 5};
    const int offsT[8] = {OFF_WA, OFF_WB, OFF_WC, OFF_WD, OFF_WE, OFF_WF, OFF_P1, OFF_P2};
    int S = NCt[ph] * KTt[ph] * 512;
    int idx = blockIdx.x * 256 + threadIdx.x;
    if (idx >= S) return;
    int tile = idx >> 9;
    int r    = idx & 511;
    int lane = r >> 3;
    int e    = r & 7;
    int KTp  = KTt[ph];
    int ct   = tile / KTp;
    int kt   = tile - ct * KTp;
    int n = ct * 16 + (lane & 15);
    int k = kt * 32 + (lane >> 4) * 8 + e;
    float val = 0.0f;
    switch (ph) {
        case 0: if (k < 68 && n < 68) { int v = k / 17; if (n / 17 == v) val = tW1[(k % 17) * 17 + (n % 17)]; } break;
        case 1: if (k < 68 && n < 168) { int v = k / 17; int c = n - 42 * v; if (c >= 0 && c < 42) val = tW2[(k % 17) * 42 + c]; } break;
        case 2: if (k < 168 && n < 272) { int v = k / 42; int c = n - 68 * v; if (c >= 0 && c < 68) val = tW3[(k % 42) * 68 + c]; } break;
        case 3: if (k < 272 && n < 272) val = gW1[k * 272 + n]; break;
        case 4: if (k < 272 && n < 170) val = gW2[k * 170 + n]; break;
        case 5: if (k < 170 && n < 68)  val = gW3[k * 68 + n]; break;
        case 6: if (k < 68 && n < 68)   val = pW1[k * 68 + n]; break;
        case 7: if (k < 68 && n < 68)   val = pW2[k * 68 + n]; break;
    }
    wts[offsT[ph] + idx] = f2bf(val);
}

// ---------------------------------------------------------------------------
// MFMA phase helpers (round-11 proven)
// ---------------------------------------------------------------------------
template<int KT, int NC>
__device__ __forceinline__ void mfma_phase(
    const unsigned short* __restrict__ wt,
    const unsigned short* __restrict__ bufIn, int ldkIn,
    unsigned short* __restrict__ bufOut, int ldkOut,
    const float* __restrict__ bias, int bmod, int Nvalid,
    int lane, int wave)
{
    #pragma unroll
    for (int rt = 0; rt < 3; ++rt) {
        short8v af[KT];
        int abase = (rt * 16 + (lane & 15)) * ldkIn + 8 * (lane >> 4);
        #pragma unroll
        for (int kt = 0; kt < KT; ++kt)
            af[kt] = *reinterpret_cast<const short8v*>(&bufIn[abase + kt * 32]);
        for (int ct = wave; ct < NC; ct += 4) {
            int c = ct * 16 + (lane & 15);
            const unsigned short* wp = wt + (size_t)(ct * KT) * 512 + lane * 8;
            short8v bf[KT];
            #pragma unroll
            for (int kt = 0; kt < KT; ++kt)
                bf[kt] = *reinterpret_cast<const short8v*>(&wp[kt * 512]);
            f32x4 acc = {0.0f, 0.0f, 0.0f, 0.0f};
            #pragma unroll
            for (int kt = 0; kt < KT; ++kt)
                acc = __builtin_amdgcn_mfma_f32_16x16x32_bf16(af[kt], bf[kt], acc, 0, 0, 0);
            float bv = 0.0f;
            if (c < Nvalid) {
                int cb = (bmod == 0) ? (c % 17) : (bmod == 1) ? (c % 42) : (bmod == 2) ? (c % 68) : c;
                bv = bias[cb];
            }
            #pragma unroll
            for (int i = 0; i < 4; ++i) {
                float vv = sigf(acc[i] + bv);
                int rl = rt * 16 + (lane >> 4) * 4 + i;
                if (c < ldkOut) bufOut[rl * ldkOut + c] = f2bf(vv);
            }
        }
    }
}

template<int KT>
__device__ __forceinline__ void mfma_final(
    const unsigned short* __restrict__ wt,
    const unsigned short* __restrict__ bufIn, int ldkIn,
    float* __restrict__ io, int baseRow,
    const float* __restrict__ gb3, int lane, int wave)
{
    #pragma unroll
    for (int rt = 0; rt < 3; ++rt) {
        short8v af[KT];
        int abase = (rt * 16 + (lane & 15)) * ldkIn + 8 * (lane >> 4);
        #pragma unroll
        for (int kt = 0; kt < KT; ++kt)
            af[kt] = *reinterpret_cast<const short8v*>(&bufIn[abase + kt * 32]);
        for (int ct = wave; ct < 5; ct += 4) {
            int c = ct * 16 + (lane & 15);
            const unsigned short* wp = wt + (size_t)(ct * KT) * 512 + lane * 8;
            short8v bf[KT];
            #pragma unroll
            for (int kt = 0; kt < KT; ++kt)
                bf[kt] = *reinterpret_cast<const short8v*>(&wp[kt * 512]);
            f32x4 acc = {0.0f, 0.0f, 0.0f, 0.0f};
            #pragma unroll
            for (int kt = 0; kt < KT; ++kt)
                acc = __builtin_amdgcn_mfma_f32_16x16x32_bf16(af[kt], bf[kt], acc, 0, 0, 0);
            float bv = (c < 68) ? gb3[c] : 0.0f;
            #pragma unroll
            for (int i = 0; i < 4; ++i) {
                int row = baseRow + rt * 16 + (lane >> 4) * 4 + i;
                if (c < 68 && row < TT) io[(size_t)row * DD + c] = acc[i] + bv;
            }
        }
    }
}

__global__ __launch_bounds__(256) void mlp_mfma(
    float* __restrict__ io, const unsigned short* __restrict__ wts,
    const float* __restrict__ tb1, const float* __restrict__ tb2, const float* __restrict__ tb3,
    const float* __restrict__ gb1, const float* __restrict__ gb2, const float* __restrict__ gb3)
{
    __shared__ unsigned short buf0[BUFSZ];
    __shared__ unsigned short buf1[BUFSZ];
    int tid = threadIdx.x, lane = tid & 63, wave = tid >> 6;
    int baseRow = blockIdx.x * MROWS;

    for (int e = tid; e < BUFSZ; e += 256) { buf0[e] = 0; buf1[e] = 0; }
    __syncthreads();
    for (int e = tid; e < MROWS * DD; e += 256) {
        int r = e / DD, c = e % DD;
        int gr = baseRow + r;
        float xv = (gr < TT) ? io[(size_t)gr * DD + c] : 0.0f;
        buf0[r * 72 + c] = f2bf(xv);
    }
    __syncthreads();
    mfma_phase<3, 5 >(wts + OFF_WA, buf0, 72,  buf1, 72,  tb1, 0, 68,  lane, wave); __syncthreads();
    mfma_phase<3, 11>(wts + OFF_WB, buf1, 72,  buf0, 168, tb2, 1, 168, lane, wave); __syncthreads();
    mfma_phase<6, 17>(wts + OFF_WC, buf0, 168, buf1, 272, tb3, 2, 272, lane, wave); __syncthreads();
    mfma_phase<9, 17>(wts + OFF_WD, buf1, 272, buf0, 272, gb1, 3, 272, lane, wave); __syncthreads();
    mfma_phase<9, 11>(wts + OFF_WE, buf0, 272, buf1, 176, gb2, 3, 170, lane, wave); __syncthreads();
    mfma_final<6>(wts + OFF_WF, buf1, 176, io, baseRow, gb3, lane, wave);
}

// ---------------------------------------------------------------------------
// enc_mfma + fused sensory table: computes VarEncoder on matrix cores, keeps
// u = h2*in_w+in_b in LDS, then computes tab (num_s,den_s) for its 48 rows.
// Tail rows t>=NB replicate row NB-1 (seq tail is a repeat by construction).
// ---------------------------------------------------------------------------
__global__ __launch_bounds__(256) void enc_mfma(
    const float* __restrict__ x, const unsigned short* __restrict__ wts,
    const float* __restrict__ pb1, const float* __restrict__ pb2,
    const float4* __restrict__ psens,
    const float* __restrict__ in_w, const float* __restrict__ in_b,
    const float* __restrict__ sens_mask,
    float2* __restrict__ tab)
{
    __shared__ unsigned short buf0[EBUFSZ];
    __shared__ unsigned short buf1[EBUFSZ];
    __shared__ float usf[MROWS][DD];
    __shared__ unsigned int sbits[UNITS];
    int tid = threadIdx.x, lane = tid & 63, wave = tid >> 6;
    int baseRow = blockIdx.x * MROWS;

    for (int e = tid; e < EBUFSZ; e += 256) { buf0[e] = 0; buf1[e] = 0; }
    if (tid < UNITS) {
        unsigned int b = 0;
        for (int s = 0; s < LEVELS; ++s)
            b |= (sens_mask[s * UNITS + tid] != 0.0f ? 1u : 0u) << s;
        sbits[tid] = b;
    }
    __syncthreads();
    for (int e = tid; e < MROWS * DD; e += 256) {
        int r = e / DD, c = e % DD;
        int gr = baseRow + r;
        float xv = (gr < NB) ? x[(size_t)gr * DD + c] : 0.0f;
        buf0[r * 72 + c] = f2bf(xv);
    }
    __syncthreads();
    mfma_phase<3, 5>(wts + OFF_P1, buf0, 72, buf1, 72, pb1, 3, 68, lane, wave);
    __syncthreads();
    #pragma unroll
    for (int rt = 0; rt < 3; ++rt) {
        short8v af[3];
        int abase = (rt * 16 + (lane & 15)) * 72 + 8 * (lane >> 4);
        #pragma unroll
        for (int kt = 0; kt < 3; ++kt)
            af[kt] = *reinterpret_cast<const short8v*>(&buf1[abase + kt * 32]);
        for (int ct = wave; ct < 5; ct += 4) {
            int c = ct * 16 + (lane & 15);
            const unsigned short* wp = wts + OFF_P2 + (size_t)(ct * 3) * 512 + lane * 8;
            short8v bf[3];
            #pragma unroll
            for (int kt = 0; kt < 3; ++kt)
                bf[kt] = *reinterpret_cast<const short8v*>(&wp[kt * 512]);
            f32x4 acc = {0.0f, 0.0f, 0.0f, 0.0f};
            #pragma unroll
            for (int kt = 0; kt < 3; ++kt)
                acc = __builtin_amdgcn_mfma_f32_16x16x32_bf16(af[kt], bf[kt], acc, 0, 0, 0);
            if (c < 68) {
                float bv = pb2[c];
                float iw = in_w[c], ib = in_b[c];
                #pragma unroll
                for (int i = 0; i < 4; ++i) {
                    int rl = rt * 16 + (lane >> 4) * 4 + i;
                    usf[rl][c] = fmaf(acc[i] + bv, iw, ib);
                }
            }
        }
    }
    __syncthreads();
    // tab epilogue: entries (r, v, j); same slot order as round-13 sens.
    for (int e = tid; e < MROWS * VARN * UNITS; e += 256) {
        int r = e / (VARN * UNITS);
        int rem = e - r * (VARN * UNITS);
        int v = rem / UNITS;
        int j = rem - v * UNITS;
        int grow = baseRow + r;
        if (grow >= NB) continue;
        unsigned int bits = sbits[j];
        float num = 0.0f, den = 0.0f;
        while (bits) {
            int s = __ffs(bits) - 1; bits &= bits - 1;
            float4 p = psens[(v * LEVELS + s) * UNITS + j];
            float g = fast_rcp(fmaf(p.x, fast_exp2(p.y * usf[r][v * LEVELS + s]), 1.0f));
            num = fmaf(p.w, g, num);
            den = fmaf(p.z, g, den);
        }
        size_t o = ((size_t)v * TT + grow) * UNITS + j;
        tab[o] = make_float2(num, den);
        if (grow == NB - 1) {
            #pragma unroll
            for (int k = 1; k <= 4; ++k) tab[o + (size_t)k * UNITS] = make_float2(num, den);
        }
    }
}

// ---------------------------------------------------------------------------
// scan: 3-way slot split (round-14 proven).
// ---------------------------------------------------------------------------
template<int MH>
__device__ void scan_body3(
    int j, int jnS, int jnV, float ownMul, float helpMul, int h1, int h2,
    int myStart, int myCnt, bool isH1,
    unsigned long long colbits, int v, int t0, int wstart, int tend,
    float cmt, float glvl, float cgl, float ow, float ob,
    const float* __restrict__ w, const float* __restrict__ sigma,
    const float* __restrict__ mu, const float* __restrict__ erev,
    const float2* __restrict__ tab, float* __restrict__ rout)
{
    int   src[MH]; float fw[MH], fc[MH], fk[MH], fwfe[MH];
    unsigned long long bits = colbits;
    for (int s = 0; s < myStart; ++s) bits &= bits - 1;
    #pragma unroll
    for (int k = 0; k < MH; ++k) {
        bool on = (k < myCnt);
        int sc = on ? (__ffsll((unsigned long long)bits) - 1) : 0;
        src[k] = sc;
        size_t pi = ((size_t)v * UNITS + sc) * UNITS + jnS;
        float sg = on ? sigma[pi] : 0.0f;
        float m  = on ? mu[pi]    : 0.0f;
        fw[k] = on ? softplusf(w[pi]) : 0.0f;
        fc[k] = fast_exp2(sg * m * LOG2E);
        fk[k] = -sg * LOG2E;
        fwfe[k] = on ? fw[k] * erev[pi] : 0.0f;
        if (on) bits &= bits - 1;
    }
    const float2* tp = tab + (size_t)v * TT * UNITS + jnV;
    float* rp = rout + (size_t)v * LEVELS + j;
    float2 nd = tp[(size_t)t0 * UNITS];
    float vreg = 0.0f;
    for (int t = t0; t < tend; ++t) {
        float2 ndc = nd;
        if (t + 1 < tend) nd = tp[(size_t)(t + 1) * UNITS];
        float bn = isH1 ? 0.0f : (glvl + ndc.x);
        float bd = isH1 ? 1.0f : (cgl + ndc.y);
        #pragma unroll
        for (int uf = 0; uf < 6; ++uf) {
            float vs[MH];
            #pragma unroll
            for (int k = 0; k < MH; ++k) vs[k] = __shfl(vreg, src[k], 64);
            float accn = 0.0f, accd = 0.0f;
            #pragma unroll
            for (int k = 0; k < MH; ++k) {
                float g = fast_rcp(fmaf(fc[k], fast_exp2(fk[k] * vs[k]), 1.0f));
                accn = fmaf(fwfe[k], g, accn);
                accd = fmaf(fw[k], g, accd);
            }
            float p1n = __shfl(accn, h1, 64);
            float p1d = __shfl(accd, h1, 64);
            float p2n = __shfl(accn, h2, 64);
            float p2d = __shfl(accd, h2, 64);
            float num = fmaf(accn, ownMul, bn) + helpMul * (p1n + p2n);
            float den = fmaf(accd, ownMul, bd) + helpMul * (p1d + p2d);
            vreg = fmaf(cmt, vreg, num) * fast_rcp(den);
        }
        if (j < MOTOR && t >= wstart) rp[(size_t)t * DD] = fmaf(vreg, ow, ob);
    }
}

__device__ void scan_body_gen(
    int j, int jn, bool hasHelp, int partner, int myStart, int myCnt, int mcMax,
    unsigned long long colbits, int v, int t0, int wstart, int tend,
    float cmt, float glvl, float cgl, float ow, float ob, bool isHelper,
    const float* __restrict__ w, const float* __restrict__ sigma,
    const float* __restrict__ mu, const float* __restrict__ erev,
    const float2* __restrict__ tab, float* __restrict__ rout)
{
    unsigned long long mybits = colbits;
    for (int s = 0; s < myStart; ++s) mybits &= mybits - 1;
    const float2* tp = tab + (size_t)v * TT * UNITS + jn;
    float* rp = rout + (size_t)v * LEVELS + j;
    float vreg = 0.0f;
    for (int t = t0; t < tend; ++t) {
        float2 ndc = tp[(size_t)t * UNITS];
        float bn = isHelper ? 0.0f : (glvl + ndc.x);
        float bd = isHelper ? 0.0f : (cgl + ndc.y);
        for (int uf = 0; uf < 6; ++uf) {
            unsigned long long bits = mybits;
            float num = bn, den = bd;
            for (int k = 0; k < mcMax; ++k) {
                bool on = (k < myCnt) && (bits != 0ull);
                int sc = on ? (__ffsll(bits) - 1) : 0;
                if (on) bits &= bits - 1;
                float vs = __shfl(vreg, sc, 64);
                size_t pi = ((size_t)v * UNITS + sc) * UNITS + jn;
                float a = on ? softplusf(w[pi]) * sigf((vs - mu[pi]) * sigma[pi]) : 0.0f;
                num = fmaf(a, on ? erev[pi] : 0.0f, num);
                den += a;
            }
            float pn = __shfl(num, partner, 64);
            float pd = __shfl(den, partner, 64);
            if (hasHelp) { num += pn; den += pd; }
            vreg = fmaf(cmt, vreg, num) * fast_rcp(den);
        }
        if (j < MOTOR && t >= wstart) rp[(size_t)t * DD] = fmaf(vreg, ow, ob);
    }
}

__global__ __launch_bounds__(256, 8) void scan_pre(
    const float2* __restrict__ tab,
    const float* __restrict__ gleak, const float* __restrict__ vleak, const float* __restrict__ cm,
    const float* __restrict__ w, const float* __restrict__ sigma,
    const float* __restrict__ mu, const float* __restrict__ erev,
    const float* __restrict__ out_w, const float* __restrict__ out_b,
    const float* __restrict__ mask,
    float* __restrict__ rout)
{
    int gwi = (blockIdx.x << 2) + (threadIdx.x >> 6);
    int j = threadIdx.x & 63;
    int v = gwi & 3;
    int chunk = gwi >> 2;
    if (chunk >= NCHUNK) return;
    int wstart = chunk * L_CHUNK;
    int tend = min(TT, wstart + L_CHUNK);
    int t0 = max(0, wstart - W_WARM);

    bool isH1   = (j >= UNITS);              // 51..63 -> cmd j-34
    bool isH2   = (j >= 30 && j < 43);       // inter-helper -> cmd j-13
    bool isCmdL = (j >= MOTOR && j < 30);
    int jnV = isH1 ? (j - 34) : j;
    int jnS = isH1 ? (j - 34) : (isH2 ? (j - 13) : j);

    unsigned long long colbits = 0ull;
    for (int i = 0; i < UNITS; ++i)
        colbits |= (unsigned long long)(mask[i * UNITS + jnS] != 0.0f ? 1 : 0) << i;
    int nf = __popcll(colbits);

    int ownIn = 0;
    if (j >= 30 && j < UNITS) {
        for (int i = 0; i < UNITS; ++i)
            ownIn |= (mask[i * UNITS + j] != 0.0f ? 1 : 0);
    }
    int bad = ownIn;
    #pragma unroll
    for (int off = 32; off; off >>= 1) bad |= __shfl_xor(bad, off, 64);

    int n1 = (nf + 2) / 3;
    int n2 = (nf - n1 + 1) / 2;
    int n3 = nf - n1 - n2;
    int myStart, myCnt;
    if (isH1)        { myStart = n1 + n2; myCnt = n3; }
    else if (isH2)   { myStart = n1;      myCnt = n2; }
    else if (isCmdL) { myStart = 0;       myCnt = n1; }
    else             { myStart = 0;       myCnt = nf; }
    float ownMul  = (isH1 || isH2) ? 0.0f : 1.0f;
    float helpMul = isCmdL ? 1.0f : 0.0f;
    int h1 = isCmdL ? (j + 34) : j;
    int h2 = isCmdL ? (j + 13) : j;

    float cmt  = softplusf(cm[v * UNITS + jnV]) * 6.0f;
    float gl   = softplusf(gleak[v * UNITS + jnV]);
    float glvl = gl * vleak[v * UNITS + jnV];
    float cgl  = cmt + gl + 1e-8f;
    float ow = (j < MOTOR) ? out_w[v * LEVELS + j] : 0.0f;
    float ob = (j < MOTOR) ? out_b[v * LEVELS + j] : 0.0f;

    int mc = myCnt;
    #pragma unroll
    for (int off = 32; off; off >>= 1) mc = max(mc, __shfl_xor(mc, off, 64));

    if (!bad && mc <= 2)
        scan_body3<2>(j, jnS, jnV, ownMul, helpMul, h1, h2, myStart, myCnt, isH1,
                      colbits, v, t0, wstart, tend, cmt, glvl, cgl, ow, ob,
                      w, sigma, mu, erev, tab, rout);
    else if (!bad && mc <= 3)
        scan_body3<3>(j, jnS, jnV, ownMul, helpMul, h1, h2, myStart, myCnt, isH1,
                      colbits, v, t0, wstart, tend, cmt, glvl, cgl, ow, ob,
                      w, sigma, mu, erev, tab, rout);
    else if (!bad && mc <= 4)
        scan_body3<4>(j, jnS, jnV, ownMul, helpMul, h1, h2, myStart, myCnt, isH1,
                      colbits, v, t0, wstart, tend, cmt, glvl, cgl, ow, ob,
                      w, sigma, mu, erev, tab, rout);
    else {
        int jn = isH1 ? (j - 34) : j;
        unsigned long long cb = 0ull;
        for (int i = 0; i < UNITS; ++i)
            cb |= (unsigned long long)(mask[i * UNITS + jn] != 0.0f ? 1 : 0) << i;
        int nfg = __popcll(cb);
        bool isCmd = (jn >= MOTOR && jn < 30);
        int nh = (nfg + 1) >> 1;
        int gs, gc;
        if (isH1)      { gs = nh; gc = nfg - nh; }
        else if (isCmd){ gs = 0;  gc = nh; }
        else           { gs = 0;  gc = nfg; }
        bool hasHelp = (!isH1) && isCmd;
        int partner = hasHelp ? (jn + 34) : j;
        float cmtg  = softplusf(cm[v * UNITS + jn]) * 6.0f;
        float glg   = softplusf(gleak[v * UNITS + jn]);
        float glvlg = glg * vleak[v * UNITS + jn];
        float cglg  = cmtg + glg + 1e-8f;
        int mg = gc;
        #pragma unroll
        for (int off = 32; off; off >>= 1) mg = max(mg, __shfl_xor(mg, off, 64));
        scan_body_gen(j, jn, hasHelp, partner, gs, gc, mg, cb, v, t0, wstart, tend,
                      cmtg, glvlg, cglg, ow, ob, isH1, w, sigma, mu, erev, tab, rout);
    }
}

// ---------------------------------------------------------------------------
// Fallback path (ws too small): round-3 proven kernels.
// ---------------------------------------------------------------------------
__global__ __launch_bounds__(128) void enc_kernel(
    const float* __restrict__ x,
    const float* __restrict__ W1, const float* __restrict__ b1,
    const float* __restrict__ W2, const float* __restrict__ b2,
    float* __restrict__ seq)
{
    int t = blockIdx.x;
    int j = threadIdx.x;
    __shared__ float xs[DD];
    __shared__ float h1[DD];
    if (j < DD) xs[j] = x[(size_t)t * DD + j];
    __syncthreads();
    if (j < DD) {
        float acc = b1[j];
        #pragma unroll 4
        for (int k = 0; k < DD; ++k) acc = fmaf(xs[k], W1[k * DD + j], acc);
        h1[j] = sigf(acc);
    }
    __syncthreads();
    if (j < DD) {
        float acc = b2[j];
        #pragma unroll 4
        for (int k = 0; k < DD; ++k) acc = fmaf(h1[k], W2[k * DD + j], acc);
        int v = j / LEVELS, s = j % LEVELS;
        float* dst = seq + ((size_t)v * TT + t) * LEVELS + s;
        dst[0] = acc;
        if (t == NB - 1) {
            dst[1 * LEVELS] = acc; dst[2 * LEVELS] = acc;
            dst[3 * LEVELS] = acc; dst[4 * LEVELS] = acc;
        }
    }
}

template<int MF, int MS>
__device__ __forceinline__ void scan_loop_f(
    int j, int v, int t0, int wstart, int tend,
    const float* __restrict__ seq, float* __restrict__ rout,
    float cmt, float glvl, float cgl, float iw, float ib, float ow, float ob,
    int nf, int ns,
    const int* rs_, const float* rw_, const float* rc_, const float* rk_, const float* re_,
    const int* ss_, const float* sw_, const float* sc_, const float* sk_, const float* se_)
{
    int fs[MF]; float fw[MF], fc[MF], fk[MF], fe[MF];
    #pragma unroll
    for (int k = 0; k < MF; ++k) {
        bool on = k < nf;
        int idx = j * CAP_R + k;
        fs[k] = on ? rs_[idx] : 0;
        fw[k] = on ? rw_[idx] : 0.0f;
        fc[k] = on ? rc_[idx] : 1.0f;
        fk[k] = on ? rk_[idx] : 0.0f;
        fe[k] = on ? re_[idx] : 0.0f;
    }
    int gs[MS]; float gw[MS], gc[MS], gk[MS], ge[MS];
    #pragma unroll
    for (int k = 0; k < MS; ++k) {
        bool on = k < ns;
        int idx = j * LEVELS + k;
        gs[k] = on ? ss_[idx] : 0;
        gw[k] = on ? sw_[idx] : 0.0f;
        gc[k] = on ? sc_[idx] : 1.0f;
        gk[k] = on ? sk_[idx] : 0.0f;
        ge[k] = on ? se_[idx] : 0.0f;
    }
    const float* sp = seq + (size_t)v * TT * LEVELS + j;
    float* rp = rout + (size_t)v * LEVELS + j;
    float xnext = (j < LEVELS) ? sp[(size_t)t0 * LEVELS] : 0.0f;
    float vreg = 0.0f;
    for (int t = t0; t < tend; ++t) {
        float u = fmaf(xnext, iw, ib);
        if (j < LEVELS && t + 1 < tend) xnext = sp[(size_t)(t + 1) * LEVELS];
        float us[MS];
        #pragma unroll
        for (int k = 0; k < MS; ++k) us[k] = __shfl(u, gs[k], 64);
        float sa[MS];
        #pragma unroll
        for (int k = 0; k < MS; ++k)
            sa[k] = gw[k] * fast_rcp(fmaf(gc[k], fast_exp2(gk[k] * us[k]), 1.0f));
        float bn = glvl, bd = cgl;
        #pragma unroll
        for (int k = 0; k < MS; ++k) { bn = fmaf(sa[k], ge[k], bn); bd += sa[k]; }
        #pragma unroll
        for (int uf = 0; uf < 6; ++uf) {
            float vsa[MF];
            #pragma unroll
            for (int k = 0; k < MF; ++k) vsa[k] = __shfl(vreg, fs[k], 64);
            float aa[MF];
            #pragma unroll
            for (int k = 0; k < MF; ++k)
                aa[k] = fw[k] * fast_rcp(fmaf(fc[k], fast_exp2(fk[k] * vsa[k]), 1.0f));
            float num = bn, den = bd;
            #pragma unroll
            for (int k = 0; k < MF; ++k) { num = fmaf(aa[k], fe[k], num); den += aa[k]; }
            vreg = fmaf(cmt, vreg, num) * fast_rcp(den);
        }
        if (j < LEVELS && t >= wstart) rp[(size_t)t * DD] = fmaf(vreg, ow, ob);
    }
}

__global__ __launch_bounds__(64) void scan_fallback(
    const float* __restrict__ seq,
    const float* __restrict__ gleak, const float* __restrict__ vleak, const float* __restrict__ cm,
    const float* __restrict__ w, const float* __restrict__ sigma,
    const float* __restrict__ mu, const float* __restrict__ erev,
    const float* __restrict__ sens_w, const float* __restrict__ sens_sigma,
    const float* __restrict__ sens_mu, const float* __restrict__ sens_erev,
    const float* __restrict__ in_w, const float* __restrict__ in_b,
    const float* __restrict__ out_w, const float* __restrict__ out_b,
    const float* __restrict__ mask, const float* __restrict__ sens_mask,
    float* __restrict__ rout)
{
    __shared__ int   rs_[UNITS * CAP_R];
    __shared__ float rw_[UNITS * CAP_R], rc_[UNITS * CAP_R], rk_[UNITS * CAP_R], re_[UNITS * CAP_R];
    __shared__ int   ss_[UNITS * LEVELS];
    __shared__ float sw_[UNITS * LEVELS], sc_[UNITS * LEVELS], sk_[UNITS * LEVELS], se_[UNITS * LEVELS];
    __shared__ int   cnts[64], scnts[64];
    __shared__ int   red[2];

    int j = threadIdx.x;
    int v = blockIdx.x & 3;
    int chunk = blockIdx.x >> 2;
    int wstart = chunk * L_F;
    if (wstart >= TT) return;
    int tend = min(TT, wstart + L_F);
    int t0 = max(0, wstart - W_F);

    int nf = 0, ns = 0;
    if (j < UNITS) {
        for (int i = 0; i < UNITS; ++i) {
            if (mask[i * UNITS + j] != 0.0f) {
                if (nf < CAP_R) {
                    size_t pi = ((size_t)v * UNITS + i) * UNITS + j;
                    int idx = j * CAP_R + nf;
                    float sg = sigma[pi], m = mu[pi];
                    rs_[idx] = i;
                    rw_[idx] = softplusf(w[pi]);
                    rc_[idx] = fast_exp2(sg * m * LOG2E);
                    rk_[idx] = -sg * LOG2E;
                    re_[idx] = erev[pi];
                }
                nf++;
            }
        }
        for (int s = 0; s < LEVELS; ++s) {
            if (sens_mask[s * UNITS + j] != 0.0f) {
                size_t pi = ((size_t)v * LEVELS + s) * UNITS + j;
                int idx = j * LEVELS + ns;
                float sg = sens_sigma[pi], m = sens_mu[pi];
                ss_[idx] = s;
                sw_[idx] = softplusf(sens_w[pi]);
                sc_[idx] = fast_exp2(sg * m * LOG2E);
                sk_[idx] = -sg * LOG2E;
                se_[idx] = sens_erev[pi];
                ns++;
            }
        }
    }
    cnts[j] = nf; scnts[j] = ns;
    __syncthreads();
    if (j == 0) {
        int mf = 0, ms = 0;
        for (int i = 0; i < UNITS; ++i) { mf = max(mf, cnts[i]); ms = max(ms, scnts[i]); }
        red[0] = mf; red[1] = ms;
    }
    __syncthreads();
    int maxF = red[0], maxS = red[1];

    int jc = (j < UNITS) ? j : (UNITS - 1);
    float cmt  = softplusf(cm[v * UNITS + jc]) * 6.0f;
    float gl   = softplusf(gleak[v * UNITS + jc]);
    float glvl = gl * vleak[v * UNITS + jc];
    float cgl  = cmt + gl + 1e-8f;
    float iw = (j < LEVELS) ? in_w[v * LEVELS + j]  : 0.0f;
    float ib = (j < LEVELS) ? in_b[v * LEVELS + j]  : 0.0f;
    float ow = (j < LEVELS) ? out_w[v * LEVELS + j] : 0.0f;
    float ob = (j < LEVELS) ? out_b[v * LEVELS + j] : 0.0f;

    if (maxF <= 11 && maxS <= 12)
        scan_loop_f<11, 12>(j, v, t0, wstart, tend, seq, rout, cmt, glvl, cgl, iw, ib, ow, ob, nf, ns,
                            rs_, rw_, rc_, rk_, re_, ss_, sw_, sc_, sk_, se_);
    else
        scan_loop_f<16, 17>(j, v, t0, wstart, tend, seq, rout, cmt, glvl, cgl, iw, ib, ow, ob, nf, ns,
                            rs_, rw_, rc_, rk_, re_, ss_, sw_, sc_, sk_, se_);
}

__global__ __launch_bounds__(256) void mlp_kernel(
    float* __restrict__ io,
    const float* __restrict__ tW1, const float* __restrict__ tb1,
    const float* __restrict__ tW2, const float* __restrict__ tb2,
    const float* __restrict__ tW3, const float* __restrict__ tb3,
    const float* __restrict__ gW1, const float* __restrict__ gb1,
    const float* __restrict__ gW2, const float* __restrict__ gb2,
    const float* __restrict__ gW3, const float* __restrict__ gb3)
{
    __shared__ __align__(16) float A[TROWS][272];
    __shared__ __align__(16) float Bf[TROWS][272];
    int base = blockIdx.x * TROWS;
    int tid = threadIdx.x;

    for (int e = tid; e < TROWS * DD; e += 256) {
        int r = e / DD, c = e % DD;
        A[r][c] = (base + r < TT) ? io[(size_t)(base + r) * DD + c] : 0.0f;
    }
    __syncthreads();
    for (int c = tid; c < 4 * LEVELS; c += 256) {
        int vv = c / LEVELS, cc = c % LEVELS;
        float acc[TROWS]; float bias = tb1[cc];
        #pragma unroll
        for (int r = 0; r < TROWS; ++r) acc[r] = bias;
        for (int k = 0; k < LEVELS; ++k) {
            float wv = tW1[k * LEVELS + cc];
            #pragma unroll
            for (int r = 0; r < TROWS; ++r) acc[r] = fmaf(A[r][vv * LEVELS + k], wv, acc[r]);
        }
        #pragma unroll
        for (int r = 0; r < TROWS; ++r) Bf[r][c] = sigf(acc[r]);
    }
    __syncthreads();
    for (int c = tid; c < 4 * 42; c += 256) {
        int vv = c / 42, cc = c % 42;
        float acc[TROWS]; float bias = tb2[cc];
        #pragma unroll
        for (int r = 0; r < TROWS; ++r) acc[r] = bias;
        for (int k = 0; k < LEVELS; ++k) {
            float wv = tW2[k * 42 + cc];
            #pragma unroll
            for (int r = 0; r < TROWS; ++r) acc[r] = fmaf(Bf[r][vv * LEVELS + k], wv, acc[r]);
        }
        #pragma unroll
        for (int r = 0; r < TROWS; ++r) A[r][vv * 42 + cc] = sigf(acc[r]);
    }
    __syncthreads();
    for (int c = tid; c < 4 * DD; c += 256) {
        int vv = c / DD, cc = c % DD;
        float acc[TROWS]; float bias = tb3[cc];
        #pragma unroll
        for (int r = 0; r < TROWS; ++r) acc[r] = bias;
        for (int k = 0; k < 42; ++k) {
            float wv = tW3[k * DD + cc];
            #pragma unroll
            for (int r = 0; r < TROWS; ++r) acc[r] = fmaf(A[r][vv * 42 + k], wv, acc[r]);
        }
        #pragma unroll
        for (int r = 0; r < TROWS; ++r) Bf[r][c] = sigf(acc[r]);
    }
    __syncthreads();
    for (int c = tid; c < 272; c += 256) {
        float acc[TROWS]; float bias = gb1[c];
        #pragma unroll
        for (int r = 0; r < TROWS; ++r) acc[r] = bias;
        for (int k = 0; k < 272; k += 4) {
            float w0 = gW1[(k + 0) * 272 + c];
            float w1 = gW1[(k + 1) * 272 + c];
            float w2 = gW1[(k + 2) * 272 + c];
            float w3 = gW1[(k + 3) * 272 + c];
            #pragma unroll
            for (int r = 0; r < TROWS; ++r) {
                float4 g4 = *reinterpret_cast<const float4*>(&Bf[r][k]);
                acc[r] = fmaf(g4.x, w0, fmaf(g4.y, w1, fmaf(g4.z, w2, fmaf(g4.w, w3, acc[r]))));
            }
        }
        #pragma unroll
        for (int r = 0; r < TROWS; ++r) A[r][c] = sigf(acc[r]);
    }
    __syncthreads();
    for (int c = tid; c < 170; c += 256) {
        float acc[TROWS]; float bias = gb2[c];
        #pragma unroll
        for (int r = 0; r < TROWS; ++r) acc[r] = bias;
        for (int k = 0; k < 272; k += 4) {
            float w0 = gW2[(k + 0) * 170 + c];
            float w1 = gW2[(k + 1) * 170 + c];
            float w2 = gW2[(k + 2) * 170 + c];
            float w3 = gW2[(k + 3) * 170 + c];
            #pragma unroll
            for (int r = 0; r < TROWS; ++r) {
                float4 g4 = *reinterpret_cast<const float4*>(&A[r][k]);
                acc[r] = fmaf(g4.x, w0, fmaf(g4.y, w1, fmaf(g4.z, w2, fmaf(g4.w, w3, acc[r]))));
            }
        }
        #pragma unroll
        for (int r = 0; r < TROWS; ++r) Bf[r][c] = sigf(acc[r]);
    }
    __syncthreads();
    for (int c = tid; c < DD; c += 256) {
        float acc[TROWS]; float bias = gb3[c];
        #pragma unroll
        for (int r = 0; r < TROWS; ++r) acc[r] = bias;
        for (int k = 0; k < 168; k += 4) {
            float w0 = gW3[(k + 0) * DD + c];
            float w1 = gW3[(k + 1) * DD + c];
            float w2 = gW3[(k + 2) * DD + c];
            float w3 = gW3[(k + 3) * DD + c];
            #pragma unroll
            for (int r = 0; r < TROWS; ++r) {
                float4 g4 = *reinterpret_cast<const float4*>(&Bf[r][k]);
                acc[r] = fmaf(g4.x, w0, fmaf(g4.y, w1, fmaf(g4.z, w2, fmaf(g4.w, w3, acc[r]))));
            }
        }
        for (int k = 168; k < 170; ++k) {
            float wv = gW3[k * DD + c];
            #pragma unroll
            for (int r = 0; r < TROWS; ++r) acc[r] = fmaf(Bf[r][k], wv, acc[r]);
        }
        #pragma unroll
        for (int r = 0; r < TROWS; ++r)
            if (base + r < TT) io[(size_t)(base + r) * DD + c] = acc[r];
    }
}

// ---------------------------------------------------------------------------
extern "C" void kernel_launch(void* const* d_in, const int* in_sizes, int n_in,
                              void* d_out, int out_size, void* d_ws, size_t ws_size,
                              hipStream_t stream)
{
    (void)in_sizes; (void)n_in; (void)out_size;
    const float* x        = (const float*)d_in[0];
    const float* pre_w1   = (const float*)d_in[1];
    const float* pre_b1   = (const float*)d_in[2];
    const float* pre_w2   = (const float*)d_in[3];
    const float* pre_b2   = (const float*)d_in[4];
    const float* gleak    = (const float*)d_in[5];
    const float* vleak    = (const float*)d_in[6];
    const float* cm       = (const float*)d_in[7];
    const float* w        = (const float*)d_in[8];
    const float* sigma    = (const float*)d_in[9];
    const float* mu       = (const float*)d_in[10];
    const float* erev     = (const float*)d_in[11];
    const float* sens_w   = (const float*)d_in[12];
    const float* sens_sig = (const float*)d_in[13];
    const float* sens_mu  = (const float*)d_in[14];
    const float* sens_er  = (const float*)d_in[15];
    const float* in_w     = (const float*)d_in[16];
    const float* in_b     = (const float*)d_in[17];
    const float* out_w    = (const float*)d_in[18];
    const float* out_b    = (const float*)d_in[19];
    const float* tW1      = (const float*)d_in[20];
    const float* tb1      = (const float*)d_in[21];
    const float* tW2      = (const float*)d_in[22];
    const float* tb2      = (const float*)d_in[23];
    const float* tW3      = (const float*)d_in[24];
    const float* tb3      = (const float*)d_in[25];
    const float* gW1      = (const float*)d_in[26];
    const float* gb1      = (const float*)d_in[27];
    const float* gW2      = (const float*)d_in[28];
    const float* gb2      = (const float*)d_in[29];
    const float* gW3      = (const float*)d_in[30];
    const float* gb3      = (const float*)d_in[31];
    const float* mask     = (const float*)d_in[32];
    const float* smask    = (const float*)d_in[33];

    float* out = (float*)d_out;

    size_t tab_bytes = (size_t)VARN * TT * UNITS * sizeof(float2);   // 53.5 MB
    size_t seq_bytes = (size_t)VARN * TT * LEVELS * sizeof(float);   // 8.9 MB (fallback only)
    size_t wts_bytes = (size_t)WTS_SHORTS * sizeof(unsigned short);  // 0.45 MB
    size_t ps_bytes  = (size_t)PSENS_N * sizeof(float4);             // 55 KB

    if (ws_size >= tab_bytes + seq_bytes + wts_bytes + ps_bytes) {
        float2* tab = (float2*)d_ws;
        unsigned short* wts = (unsigned short*)((char*)d_ws + tab_bytes + seq_bytes);
        float4* psens = (float4*)((char*)d_ws + tab_bytes + seq_bytes + wts_bytes);
        prep_all<<<dim3(306, 9), 256, 0, stream>>>(
            tW1, tW2, tW3, gW1, gW2, gW3, pre_w1, pre_w2,
            sens_w, sens_sig, sens_mu, sens_er, wts, psens);
        enc_mfma<<<EBLK, 256, 0, stream>>>(
            x, wts, pre_b1, pre_b2, psens, in_w, in_b, smask, tab);
        scan_pre<<<NCHUNK, 256, 0, stream>>>(
            tab, gleak, vleak, cm, w, sigma, mu, erev, out_w, out_b, mask, out);
        mlp_mfma<<<MBLK, 256, 0, stream>>>(out, wts, tb1, tb2, tb3, gb1, gb2, gb3);
    } else if (ws_size >= seq_bytes) {
        float* seq = (float*)d_ws;
        enc_kernel<<<NB, 128, 0, stream>>>(x, pre_w1, pre_b1, pre_w2, pre_b2, seq);
        scan_fallback<<<VARN * NCHUNK_F, 64, 0, stream>>>(
            seq, gleak, vleak, cm, w, sigma, mu, erev,
            sens_w, sens_sig, sens_mu, sens_er,
            in_w, in_b, out_w, out_b, mask, smask, out);
        mlp_kernel<<<(TT + TROWS - 1) / TROWS, 256, 0, stream>>>(
            out, tW1, tb1, tW2, tb2, tW3, tb3, gW1, gb1, gW2, gb2, gW3, gb3);
    }
}

// Round 16
// 222.996 us; speedup vs baseline: 1.0761x; 1.0761x over previous
//
#include <hip/hip_runtime.h>
#include <hip/hip_bf16.h>
#include <math.h>

#define LEVELS 17
#define VARN   4
#define UNITS  51
#define MOTOR  17
#define NB     32768
#define TT     (NB + 4)      // 32772
#define DD     68
#define LOG2E  1.4426950408889634f
#define TROWS  16

// scan geometry (round-14 proven: L=34 is the occupancy/step-count sweet spot)
#define W_WARM  10
#define L_CHUNK 34
#define NCHUNK  ((TT + L_CHUNK - 1) / L_CHUNK)   // 965 blocks (4 waves each)

// fallback geometry
#define W_F     64
#define L_F     64
#define NCHUNK_F ((TT + L_F - 1) / L_F)
#define CAP_R  16

// MFMA MLP geometry
#define MROWS  48
#define MBLK   ((TT + MROWS - 1) / MROWS)
#define EBLK   ((NB + MROWS - 1) / MROWS)
#define BUFSZ  (48 * 272 + 64)
#define EBUFSZ (48 * 72 + 64)

// weight table offsets (shorts), fragment-packed layout (round-11 proven)
#define OFF_WA 0
#define OFF_WB 7680
#define OFF_WC 24576
#define OFF_WD 76800
#define OFF_WE 155136
#define OFF_WF 205824
#define OFF_P1 221184
#define OFF_P2 228864
#define WTS_SHORTS 236544
#define PSENS_N (VARN * LEVELS * UNITS)          // 3468 float4 = 55 KB

typedef __attribute__((ext_vector_type(8))) short short8v;
typedef __attribute__((ext_vector_type(4))) float f32x4;

__device__ __forceinline__ float fast_rcp(float x) { return __builtin_amdgcn_rcpf(x); }
__device__ __forceinline__ float fast_exp2(float x) { return __builtin_amdgcn_exp2f(x); }
__device__ __forceinline__ float sigf(float x) { return fast_rcp(1.0f + __expf(-x)); }
__device__ __forceinline__ float softplusf(float x) { return logf(1.0f + expf(x)); }
__device__ __forceinline__ unsigned short f2bf(float x) {
    unsigned int u = __float_as_uint(x);
    unsigned int r = u + 0x7FFFu + ((u >> 16) & 1u);
    return (unsigned short)(r >> 16);
}

// ---------------------------------------------------------------------------
// prep_all: fragment-packed weights (ph 0..7) + folded sensory table (ph 8).
// ---------------------------------------------------------------------------
__global__ __launch_bounds__(256) void prep_all(
    const float* __restrict__ tW1, const float* __restrict__ tW2, const float* __restrict__ tW3,
    const float* __restrict__ gW1, const float* __restrict__ gW2, const float* __restrict__ gW3,
    const float* __restrict__ pW1, const float* __restrict__ pW2,
    const float* __restrict__ sens_w, const float* __restrict__ sens_sigma,
    const float* __restrict__ sens_mu, const float* __restrict__ sens_erev,
    unsigned short* __restrict__ wts, float4* __restrict__ psens)
{
    const int ph = blockIdx.y;
    if (ph == 8) {
        int idx = blockIdx.x * 256 + threadIdx.x;
        if (idx >= PSENS_N) return;
        float sg = sens_sigma[idx], m = sens_mu[idx];
        float wf = softplusf(sens_w[idx]);
        psens[idx] = make_float4(fast_exp2(sg * m * LOG2E), -sg * LOG2E, wf, wf * sens_erev[idx]);
        return;
    }
    const int KTt[8]   = {3, 3, 6, 9, 9, 6, 3, 3};
    const int NCt[8]   = {5, 11, 17, 17, 11, 5, 5, 5};
    const int offsT[8] = {OFF_WA, OFF_WB, OFF_WC, OFF_WD, OFF_WE, OFF_WF, OFF_P1, OFF_P2};
    int S = NCt[ph] * KTt[ph] * 512;
    int idx = blockIdx.x * 256 + threadIdx.x;
    if (idx >= S) return;
    int tile = idx >> 9;
    int r    = idx & 511;
    int lane = r >> 3;
    int e    = r & 7;
    int KTp  = KTt[ph];
    int ct   = tile / KTp;
    int kt   = tile - ct * KTp;
    int n = ct * 16 + (lane & 15);
    int k = kt * 32 + (lane >> 4) * 8 + e;
    float val = 0.0f;
    switch (ph) {
        case 0: if (k < 68 && n < 68) { int v = k / 17; if (n / 17 == v) val = tW1[(k % 17) * 17 + (n % 17)]; } break;
        case 1: if (k < 68 && n < 168) { int v = k / 17; int c = n - 42 * v; if (c >= 0 && c < 42) val = tW2[(k % 17) * 42 + c]; } break;
        case 2: if (k < 168 && n < 272) { int v = k / 42; int c = n - 68 * v; if (c >= 0 && c < 68) val = tW3[(k % 42) * 68 + c]; } break;
        case 3: if (k < 272 && n < 272) val = gW1[k * 272 + n]; break;
        case 4: if (k < 272 && n < 170) val = gW2[k * 170 + n]; break;
        case 5: if (k < 170 && n < 68)  val = gW3[k * 68 + n]; break;
        case 6: if (k < 68 && n < 68)   val = pW1[k * 68 + n]; break;
        case 7: if (k < 68 && n < 68)   val = pW2[k * 68 + n]; break;
    }
    wts[offsT[ph] + idx] = f2bf(val);
}

// ---------------------------------------------------------------------------
// MFMA phase helpers (round-11 proven)
// ---------------------------------------------------------------------------
template<int KT, int NC>
__device__ __forceinline__ void mfma_phase(
    const unsigned short* __restrict__ wt,
    const unsigned short* __restrict__ bufIn, int ldkIn,
    unsigned short* __restrict__ bufOut, int ldkOut,
    const float* __restrict__ bias, int bmod, int Nvalid,
    int lane, int wave)
{
    #pragma unroll
    for (int rt = 0; rt < 3; ++rt) {
        short8v af[KT];
        int abase = (rt * 16 + (lane & 15)) * ldkIn + 8 * (lane >> 4);
        #pragma unroll
        for (int kt = 0; kt < KT; ++kt)
            af[kt] = *reinterpret_cast<const short8v*>(&bufIn[abase + kt * 32]);
        for (int ct = wave; ct < NC; ct += 4) {
            int c = ct * 16 + (lane & 15);
            const unsigned short* wp = wt + (size_t)(ct * KT) * 512 + lane * 8;
            short8v bf[KT];
            #pragma unroll
            for (int kt = 0; kt < KT; ++kt)
                bf[kt] = *reinterpret_cast<const short8v*>(&wp[kt * 512]);
            f32x4 acc = {0.0f, 0.0f, 0.0f, 0.0f};
            #pragma unroll
            for (int kt = 0; kt < KT; ++kt)
                acc = __builtin_amdgcn_mfma_f32_16x16x32_bf16(af[kt], bf[kt], acc, 0, 0, 0);
            float bv = 0.0f;
            if (c < Nvalid) {
                int cb = (bmod == 0) ? (c % 17) : (bmod == 1) ? (c % 42) : (bmod == 2) ? (c % 68) : c;
                bv = bias[cb];
            }
            #pragma unroll
            for (int i = 0; i < 4; ++i) {
                float vv = sigf(acc[i] + bv);
                int rl = rt * 16 + (lane >> 4) * 4 + i;
                if (c < ldkOut) bufOut[rl * ldkOut + c] = f2bf(vv);
            }
        }
    }
}

template<int KT>
__device__ __forceinline__ void mfma_final(
    const unsigned short* __restrict__ wt,
    const unsigned short* __restrict__ bufIn, int ldkIn,
    float* __restrict__ io, int baseRow,
    const float* __restrict__ gb3, int lane, int wave)
{
    #pragma unroll
    for (int rt = 0; rt < 3; ++rt) {
        short8v af[KT];
        int abase = (rt * 16 + (lane & 15)) * ldkIn + 8 * (lane >> 4);
        #pragma unroll
        for (int kt = 0; kt < KT; ++kt)
            af[kt] = *reinterpret_cast<const short8v*>(&bufIn[abase + kt * 32]);
        for (int ct = wave; ct < 5; ct += 4) {
            int c = ct * 16 + (lane & 15);
            const unsigned short* wp = wt + (size_t)(ct * KT) * 512 + lane * 8;
            short8v bf[KT];
            #pragma unroll
            for (int kt = 0; kt < KT; ++kt)
                bf[kt] = *reinterpret_cast<const short8v*>(&wp[kt * 512]);
            f32x4 acc = {0.0f, 0.0f, 0.0f, 0.0f};
            #pragma unroll
            for (int kt = 0; kt < KT; ++kt)
                acc = __builtin_amdgcn_mfma_f32_16x16x32_bf16(af[kt], bf[kt], acc, 0, 0, 0);
            float bv = (c < 68) ? gb3[c] : 0.0f;
            #pragma unroll
            for (int i = 0; i < 4; ++i) {
                int row = baseRow + rt * 16 + (lane >> 4) * 4 + i;
                if (c < 68 && row < TT) io[(size_t)row * DD + c] = acc[i] + bv;
            }
        }
    }
}

__global__ __launch_bounds__(256) void mlp_mfma(
    float* __restrict__ io, const unsigned short* __restrict__ wts,
    const float* __restrict__ tb1, const float* __restrict__ tb2, const float* __restrict__ tb3,
    const float* __restrict__ gb1, const float* __restrict__ gb2, const float* __restrict__ gb3)
{
    __shared__ unsigned short buf0[BUFSZ];
    __shared__ unsigned short buf1[BUFSZ];
    int tid = threadIdx.x, lane = tid & 63, wave = tid >> 6;
    int baseRow = blockIdx.x * MROWS;

    for (int e = tid; e < BUFSZ; e += 256) { buf0[e] = 0; buf1[e] = 0; }
    __syncthreads();
    for (int e = tid; e < MROWS * DD; e += 256) {
        int r = e / DD, c = e % DD;
        int gr = baseRow + r;
        float xv = (gr < TT) ? io[(size_t)gr * DD + c] : 0.0f;
        buf0[r * 72 + c] = f2bf(xv);
    }
    __syncthreads();
    mfma_phase<3, 5 >(wts + OFF_WA, buf0, 72,  buf1, 72,  tb1, 0, 68,  lane, wave); __syncthreads();
    mfma_phase<3, 11>(wts + OFF_WB, buf1, 72,  buf0, 168, tb2, 1, 168, lane, wave); __syncthreads();
    mfma_phase<6, 17>(wts + OFF_WC, buf0, 168, buf1, 272, tb3, 2, 272, lane, wave); __syncthreads();
    mfma_phase<9, 17>(wts + OFF_WD, buf1, 272, buf0, 272, gb1, 3, 272, lane, wave); __syncthreads();
    mfma_phase<9, 11>(wts + OFF_WE, buf0, 272, buf1, 176, gb2, 3, 170, lane, wave); __syncthreads();
    mfma_final<6>(wts + OFF_WF, buf1, 176, io, baseRow, gb3, lane, wave);
}

__global__ __launch_bounds__(256) void enc_mfma(
    const float* __restrict__ x, const unsigned short* __restrict__ wts,
    const float* __restrict__ pb1, const float* __restrict__ pb2,
    float* __restrict__ seq)
{
    __shared__ unsigned short buf0[EBUFSZ];
    __shared__ unsigned short buf1[EBUFSZ];
    int tid = threadIdx.x, lane = tid & 63, wave = tid >> 6;
    int baseRow = blockIdx.x * MROWS;

    for (int e = tid; e < EBUFSZ; e += 256) { buf0[e] = 0; buf1[e] = 0; }
    __syncthreads();
    for (int e = tid; e < MROWS * DD; e += 256) {
        int r = e / DD, c = e % DD;
        int gr = baseRow + r;
        float xv = (gr < NB) ? x[(size_t)gr * DD + c] : 0.0f;
        buf0[r * 72 + c] = f2bf(xv);
    }
    __syncthreads();
    mfma_phase<3, 5>(wts + OFF_P1, buf0, 72, buf1, 72, pb1, 3, 68, lane, wave);
    __syncthreads();
    #pragma unroll
    for (int rt = 0; rt < 3; ++rt) {
        short8v af[3];
        int abase = (rt * 16 + (lane & 15)) * 72 + 8 * (lane >> 4);
        #pragma unroll
        for (int kt = 0; kt < 3; ++kt)
            af[kt] = *reinterpret_cast<const short8v*>(&buf1[abase + kt * 32]);
        for (int ct = wave; ct < 5; ct += 4) {
            int c = ct * 16 + (lane & 15);
            const unsigned short* wp = wts + OFF_P2 + (size_t)(ct * 3) * 512 + lane * 8;
            short8v bf[3];
            #pragma unroll
            for (int kt = 0; kt < 3; ++kt)
                bf[kt] = *reinterpret_cast<const short8v*>(&wp[kt * 512]);
            f32x4 acc = {0.0f, 0.0f, 0.0f, 0.0f};
            #pragma unroll
            for (int kt = 0; kt < 3; ++kt)
                acc = __builtin_amdgcn_mfma_f32_16x16x32_bf16(af[kt], bf[kt], acc, 0, 0, 0);
            float bv = (c < 68) ? pb2[c] : 0.0f;
            #pragma unroll
            for (int i = 0; i < 4; ++i) {
                int row = baseRow + rt * 16 + (lane >> 4) * 4 + i;
                if (c < 68 && row < NB) {
                    float vv = acc[i] + bv;
                    int v = c / 17, s = c % 17;
                    float* dst = seq + ((size_t)v * TT + row) * LEVELS + s;
                    dst[0] = vv;
                    if (row == NB - 1) {
                        dst[1 * LEVELS] = vv; dst[2 * LEVELS] = vv;
                        dst[3 * LEVELS] = vv; dst[4 * LEVELS] = vv;
                    }
                }
            }
        }
    }
}

// ---------------------------------------------------------------------------
// sens_kernel (round-13 proven): one wave per (v, 16-t slab).
// ---------------------------------------------------------------------------
#define SENS_TPW 16
__global__ __launch_bounds__(256) void sens_kernel(
    const float* __restrict__ seq,
    const float4* __restrict__ psens,
    const float* __restrict__ in_w, const float* __restrict__ in_b,
    const float* __restrict__ sens_mask,
    float2* __restrict__ tab)
{
    int gwi = blockIdx.x * 4 + (threadIdx.x >> 6);
    int j   = threadIdx.x & 63;
    int v    = gwi & 3;
    int tbase = (gwi >> 2) * SENS_TPW;
    if (tbase >= TT) return;

    unsigned int bits0 = 0;
    if (j < UNITS)
        for (int s = 0; s < LEVELS; ++s)
            bits0 |= (sens_mask[s * UNITS + j] != 0.0f ? 1u : 0u) << s;
    int ns = __popc(bits0);
    int mS = ns;
    #pragma unroll
    for (int off = 32; off; off >>= 1) mS = max(mS, __shfl_xor(mS, off, 64));

    float iw = (j < LEVELS) ? in_w[v * LEVELS + j] : 0.0f;
    float ib = (j < LEVELS) ? in_b[v * LEVELS + j] : 0.0f;

    int tend = min(TT, tbase + SENS_TPW);
    for (int t = tbase; t < tend; ++t) {
        float u = (j < LEVELS)
            ? fmaf(seq[((size_t)v * TT + t) * LEVELS + j], iw, ib) : 0.0f;
        unsigned int bits = bits0;
        float num = 0.0f, den = 0.0f;
        for (int k = 0; k < mS; ++k) {
            bool on = (k < ns) && (bits != 0u);
            int s = on ? (__ffs(bits) - 1) : 0;
            if (on) bits &= bits - 1;
            float us = __shfl(u, s, 64);
            float4 p = psens[(v * LEVELS + s) * UNITS + (j < UNITS ? j : 0)];
            float g = fast_rcp(fmaf(p.x, fast_exp2(p.y * us), 1.0f));
            if (on) { num = fmaf(p.w, g, num); den = fmaf(p.z, g, den); }
        }
        if (j < UNITS)
            tab[((size_t)v * TT + t) * UNITS + j] = make_float2(num, den);
    }
}

// ---------------------------------------------------------------------------
// scan: 3-way slot split (round-14 proven).
// ---------------------------------------------------------------------------
template<int MH>
__device__ void scan_body3(
    int j, int jnS, int jnV, float ownMul, float helpMul, int h1, int h2,
    int myStart, int myCnt, bool isH1,
    unsigned long long colbits, int v, int t0, int wstart, int tend,
    float cmt, float glvl, float cgl, float ow, float ob,
    const float* __restrict__ w, const float* __restrict__ sigma,
    const float* __restrict__ mu, const float* __restrict__ erev,
    const float2* __restrict__ tab, float* __restrict__ rout)
{
    int   src[MH]; float fw[MH], fc[MH], fk[MH], fwfe[MH];
    unsigned long long bits = colbits;
    for (int s = 0; s < myStart; ++s) bits &= bits - 1;
    #pragma unroll
    for (int k = 0; k < MH; ++k) {
        bool on = (k < myCnt);
        int sc = on ? (__ffsll((unsigned long long)bits) - 1) : 0;
        src[k] = sc;
        size_t pi = ((size_t)v * UNITS + sc) * UNITS + jnS;
        float sg = on ? sigma[pi] : 0.0f;
        float m  = on ? mu[pi]    : 0.0f;
        fw[k] = on ? softplusf(w[pi]) : 0.0f;
        fc[k] = fast_exp2(sg * m * LOG2E);
        fk[k] = -sg * LOG2E;
        fwfe[k] = on ? fw[k] * erev[pi] : 0.0f;
        if (on) bits &= bits - 1;
    }
    const float2* tp = tab + (size_t)v * TT * UNITS + jnV;
    float* rp = rout + (size_t)v * LEVELS + j;
    float2 nd = tp[(size_t)t0 * UNITS];
    float vreg = 0.0f;
    for (int t = t0; t < tend; ++t) {
        float2 ndc = nd;
        if (t + 1 < tend) nd = tp[(size_t)(t + 1) * UNITS];
        float bn = isH1 ? 0.0f : (glvl + ndc.x);
        float bd = isH1 ? 1.0f : (cgl + ndc.y);
        #pragma unroll
        for (int uf = 0; uf < 6; ++uf) {
            float vs[MH];
            #pragma unroll
            for (int k = 0; k < MH; ++k) vs[k] = __shfl(vreg, src[k], 64);
            float accn = 0.0f, accd = 0.0f;
            #pragma unroll
            for (int k = 0; k < MH; ++k) {
                float g = fast_rcp(fmaf(fc[k], fast_exp2(fk[k] * vs[k]), 1.0f));
                accn = fmaf(fwfe[k], g, accn);
                accd = fmaf(fw[k], g, accd);
            }
            float p1n = __shfl(accn, h1, 64);
            float p1d = __shfl(accd, h1, 64);
            float p2n = __shfl(accn, h2, 64);
            float p2d = __shfl(accd, h2, 64);
            float num = fmaf(accn, ownMul, bn) + helpMul * (p1n + p2n);
            float den = fmaf(accd, ownMul, bd) + helpMul * (p1d + p2d);
            vreg = fmaf(cmt, vreg, num) * fast_rcp(den);
        }
        if (j < MOTOR && t >= wstart) rp[(size_t)t * DD] = fmaf(vreg, ow, ob);
    }
}

__device__ void scan_body_gen(
    int j, int jn, bool hasHelp, int partner, int myStart, int myCnt, int mcMax,
    unsigned long long colbits, int v, int t0, int wstart, int tend,
    float cmt, float glvl, float cgl, float ow, float ob, bool isHelper,
    const float* __restrict__ w, const float* __restrict__ sigma,
    const float* __restrict__ mu, const float* __restrict__ erev,
    const float2* __restrict__ tab, float* __restrict__ rout)
{
    unsigned long long mybits = colbits;
    for (int s = 0; s < myStart; ++s) mybits &= mybits - 1;
    const float2* tp = tab + (size_t)v * TT * UNITS + jn;
    float* rp = rout + (size_t)v * LEVELS + j;
    float vreg = 0.0f;
    for (int t = t0; t < tend; ++t) {
        float2 ndc = tp[(size_t)t * UNITS];
        float bn = isHelper ? 0.0f : (glvl + ndc.x);
        float bd = isHelper ? 0.0f : (cgl + ndc.y);
        for (int uf = 0; uf < 6; ++uf) {
            unsigned long long bits = mybits;
            float num = bn, den = bd;
            for (int k = 0; k < mcMax; ++k) {
                bool on = (k < myCnt) && (bits != 0ull);
                int sc = on ? (__ffsll(bits) - 1) : 0;
                if (on) bits &= bits - 1;
                float vs = __shfl(vreg, sc, 64);
                size_t pi = ((size_t)v * UNITS + sc) * UNITS + jn;
                float a = on ? softplusf(w[pi]) * sigf((vs - mu[pi]) * sigma[pi]) : 0.0f;
                num = fmaf(a, on ? erev[pi] : 0.0f, num);
                den += a;
            }
            float pn = __shfl(num, partner, 64);
            float pd = __shfl(den, partner, 64);
            if (hasHelp) { num += pn; den += pd; }
            vreg = fmaf(cmt, vreg, num) * fast_rcp(den);
        }
        if (j < MOTOR && t >= wstart) rp[(size_t)t * DD] = fmaf(vreg, ow, ob);
    }
}

__global__ __launch_bounds__(256, 8) void scan_pre(
    const float2* __restrict__ tab,
    const float* __restrict__ gleak, const float* __restrict__ vleak, const float* __restrict__ cm,
    const float* __restrict__ w, const float* __restrict__ sigma,
    const float* __restrict__ mu, const float* __restrict__ erev,
    const float* __restrict__ out_w, const float* __restrict__ out_b,
    const float* __restrict__ mask,
    float* __restrict__ rout)
{
    int gwi = (blockIdx.x << 2) + (threadIdx.x >> 6);
    int j = threadIdx.x & 63;
    int v = gwi & 3;
    int chunk = gwi >> 2;
    if (chunk >= NCHUNK) return;
    int wstart = chunk * L_CHUNK;
    int tend = min(TT, wstart + L_CHUNK);
    int t0 = max(0, wstart - W_WARM);

    bool isH1   = (j >= UNITS);              // 51..63 -> cmd j-34
    bool isH2   = (j >= 30 && j < 43);       // inter-helper -> cmd j-13
    bool isCmdL = (j >= MOTOR && j < 30);
    int jnV = isH1 ? (j - 34) : j;
    int jnS = isH1 ? (j - 34) : (isH2 ? (j - 13) : j);

    unsigned long long colbits = 0ull;
    for (int i = 0; i < UNITS; ++i)
        colbits |= (unsigned long long)(mask[i * UNITS + jnS] != 0.0f ? 1 : 0) << i;
    int nf = __popcll(colbits);

    int ownIn = 0;
    if (j >= 30 && j < UNITS) {
        for (int i = 0; i < UNITS; ++i)
            ownIn |= (mask[i * UNITS + j] != 0.0f ? 1 : 0);
    }
    int bad = ownIn;
    #pragma unroll
    for (int off = 32; off; off >>= 1) bad |= __shfl_xor(bad, off, 64);

    int n1 = (nf + 2) / 3;
    int n2 = (nf - n1 + 1) / 2;
    int n3 = nf - n1 - n2;
    int myStart, myCnt;
    if (isH1)        { myStart = n1 + n2; myCnt = n3; }
    else if (isH2)   { myStart = n1;      myCnt = n2; }
    else if (isCmdL) { myStart = 0;       myCnt = n1; }
    else             { myStart = 0;       myCnt = nf; }
    float ownMul  = (isH1 || isH2) ? 0.0f : 1.0f;
    float helpMul = isCmdL ? 1.0f : 0.0f;
    int h1 = isCmdL ? (j + 34) : j;
    int h2 = isCmdL ? (j + 13) : j;

    float cmt  = softplusf(cm[v * UNITS + jnV]) * 6.0f;
    float gl   = softplusf(gleak[v * UNITS + jnV]);
    float glvl = gl * vleak[v * UNITS + jnV];
    float cgl  = cmt + gl + 1e-8f;
    float ow = (j < MOTOR) ? out_w[v * LEVELS + j] : 0.0f;
    float ob = (j < MOTOR) ? out_b[v * LEVELS + j] : 0.0f;

    int mc = myCnt;
    #pragma unroll
    for (int off = 32; off; off >>= 1) mc = max(mc, __shfl_xor(mc, off, 64));

    if (!bad && mc <= 2)
        scan_body3<2>(j, jnS, jnV, ownMul, helpMul, h1, h2, myStart, myCnt, isH1,
                      colbits, v, t0, wstart, tend, cmt, glvl, cgl, ow, ob,
                      w, sigma, mu, erev, tab, rout);
    else if (!bad && mc <= 3)
        scan_body3<3>(j, jnS, jnV, ownMul, helpMul, h1, h2, myStart, myCnt, isH1,
                      colbits, v, t0, wstart, tend, cmt, glvl, cgl, ow, ob,
                      w, sigma, mu, erev, tab, rout);
    else if (!bad && mc <= 4)
        scan_body3<4>(j, jnS, jnV, ownMul, helpMul, h1, h2, myStart, myCnt, isH1,
                      colbits, v, t0, wstart, tend, cmt, glvl, cgl, ow, ob,
                      w, sigma, mu, erev, tab, rout);
    else {
        int jn = isH1 ? (j - 34) : j;
        unsigned long long cb = 0ull;
        for (int i = 0; i < UNITS; ++i)
            cb |= (unsigned long long)(mask[i * UNITS + jn] != 0.0f ? 1 : 0) << i;
        int nfg = __popcll(cb);
        bool isCmd = (jn >= MOTOR && jn < 30);
        int nh = (nfg + 1) >> 1;
        int gs, gc;
        if (isH1)      { gs = nh; gc = nfg - nh; }
        else if (isCmd){ gs = 0;  gc = nh; }
        else           { gs = 0;  gc = nfg; }
        bool hasHelp = (!isH1) && isCmd;
        int partner = hasHelp ? (jn + 34) : j;
        float cmtg  = softplusf(cm[v * UNITS + jn]) * 6.0f;
        float glg   = softplusf(gleak[v * UNITS + jn]);
        float glvlg = glg * vleak[v * UNITS + jn];
        float cglg  = cmtg + glg + 1e-8f;
        int mg = gc;
        #pragma unroll
        for (int off = 32; off; off >>= 1) mg = max(mg, __shfl_xor(mg, off, 64));
        scan_body_gen(j, jn, hasHelp, partner, gs, gc, mg, cb, v, t0, wstart, tend,
                      cmtg, glvlg, cglg, ow, ob, isH1, w, sigma, mu, erev, tab, rout);
    }
}

// ---------------------------------------------------------------------------
// Fallback path (ws too small): round-3 proven kernels.
// ---------------------------------------------------------------------------
__global__ __launch_bounds__(128) void enc_kernel(
    const float* __restrict__ x,
    const float* __restrict__ W1, const float* __restrict__ b1,
    const float* __restrict__ W2, const float* __restrict__ b2,
    float* __restrict__ seq)
{
    int t = blockIdx.x;
    int j = threadIdx.x;
    __shared__ float xs[DD];
    __shared__ float h1[DD];
    if (j < DD) xs[j] = x[(size_t)t * DD + j];
    __syncthreads();
    if (j < DD) {
        float acc = b1[j];
        #pragma unroll 4
        for (int k = 0; k < DD; ++k) acc = fmaf(xs[k], W1[k * DD + j], acc);
        h1[j] = sigf(acc);
    }
    __syncthreads();
    if (j < DD) {
        float acc = b2[j];
        #pragma unroll 4
        for (int k = 0; k < DD; ++k) acc = fmaf(h1[k], W2[k * DD + j], acc);
        int v = j / LEVELS, s = j % LEVELS;
        float* dst = seq + ((size_t)v * TT + t) * LEVELS + s;
        dst[0] = acc;
        if (t == NB - 1) {
            dst[1 * LEVELS] = acc; dst[2 * LEVELS] = acc;
            dst[3 * LEVELS] = acc; dst[4 * LEVELS] = acc;
        }
    }
}

template<int MF, int MS>
__device__ __forceinline__ void scan_loop_f(
    int j, int v, int t0, int wstart, int tend,
    const float* __restrict__ seq, float* __restrict__ rout,
    float cmt, float glvl, float cgl, float iw, float ib, float ow, float ob,
    int nf, int ns,
    const int* rs_, const float* rw_, const float* rc_, const float* rk_, const float* re_,
    const int* ss_, const float* sw_, const float* sc_, const float* sk_, const float* se_)
{
    int fs[MF]; float fw[MF], fc[MF], fk[MF], fe[MF];
    #pragma unroll
    for (int k = 0; k < MF; ++k) {
        bool on = k < nf;
        int idx = j * CAP_R + k;
        fs[k] = on ? rs_[idx] : 0;
        fw[k] = on ? rw_[idx] : 0.0f;
        fc[k] = on ? rc_[idx] : 1.0f;
        fk[k] = on ? rk_[idx] : 0.0f;
        fe[k] = on ? re_[idx] : 0.0f;
    }
    int gs[MS]; float gw[MS], gc[MS], gk[MS], ge[MS];
    #pragma unroll
    for (int k = 0; k < MS; ++k) {
        bool on = k < ns;
        int idx = j * LEVELS + k;
        gs[k] = on ? ss_[idx] : 0;
        gw[k] = on ? sw_[idx] : 0.0f;
        gc[k] = on ? sc_[idx] : 1.0f;
        gk[k] = on ? sk_[idx] : 0.0f;
        ge[k] = on ? se_[idx] : 0.0f;
    }
    const float* sp = seq + (size_t)v * TT * LEVELS + j;
    float* rp = rout + (size_t)v * LEVELS + j;
    float xnext = (j < LEVELS) ? sp[(size_t)t0 * LEVELS] : 0.0f;
    float vreg = 0.0f;
    for (int t = t0; t < tend; ++t) {
        float u = fmaf(xnext, iw, ib);
        if (j < LEVELS && t + 1 < tend) xnext = sp[(size_t)(t + 1) * LEVELS];
        float us[MS];
        #pragma unroll
        for (int k = 0; k < MS; ++k) us[k] = __shfl(u, gs[k], 64);
        float sa[MS];
        #pragma unroll
        for (int k = 0; k < MS; ++k)
            sa[k] = gw[k] * fast_rcp(fmaf(gc[k], fast_exp2(gk[k] * us[k]), 1.0f));
        float bn = glvl, bd = cgl;
        #pragma unroll
        for (int k = 0; k < MS; ++k) { bn = fmaf(sa[k], ge[k], bn); bd += sa[k]; }
        #pragma unroll
        for (int uf = 0; uf < 6; ++uf) {
            float vsa[MF];
            #pragma unroll
            for (int k = 0; k < MF; ++k) vsa[k] = __shfl(vreg, fs[k], 64);
            float aa[MF];
            #pragma unroll
            for (int k = 0; k < MF; ++k)
                aa[k] = fw[k] * fast_rcp(fmaf(fc[k], fast_exp2(fk[k] * vsa[k]), 1.0f));
            float num = bn, den = bd;
            #pragma unroll
            for (int k = 0; k < MF; ++k) { num = fmaf(aa[k], fe[k], num); den += aa[k]; }
            vreg = fmaf(cmt, vreg, num) * fast_rcp(den);
        }
        if (j < LEVELS && t >= wstart) rp[(size_t)t * DD] = fmaf(vreg, ow, ob);
    }
}

__global__ __launch_bounds__(64) void scan_fallback(
    const float* __restrict__ seq,
    const float* __restrict__ gleak, const float* __restrict__ vleak, const float* __restrict__ cm,
    const float* __restrict__ w, const float* __restrict__ sigma,
    const float* __restrict__ mu, const float* __restrict__ erev,
    const float* __restrict__ sens_w, const float* __restrict__ sens_sigma,
    const float* __restrict__ sens_mu, const float* __restrict__ sens_erev,
    const float* __restrict__ in_w, const float* __restrict__ in_b,
    const float* __restrict__ out_w, const float* __restrict__ out_b,
    const float* __restrict__ mask, const float* __restrict__ sens_mask,
    float* __restrict__ rout)
{
    __shared__ int   rs_[UNITS * CAP_R];
    __shared__ float rw_[UNITS * CAP_R], rc_[UNITS * CAP_R], rk_[UNITS * CAP_R], re_[UNITS * CAP_R];
    __shared__ int   ss_[UNITS * LEVELS];
    __shared__ float sw_[UNITS * LEVELS], sc_[UNITS * LEVELS], sk_[UNITS * LEVELS], se_[UNITS * LEVELS];
    __shared__ int   cnts[64], scnts[64];
    __shared__ int   red[2];

    int j = threadIdx.x;
    int v = blockIdx.x & 3;
    int chunk = blockIdx.x >> 2;
    int wstart = chunk * L_F;
    if (wstart >= TT) return;
    int tend = min(TT, wstart + L_F);
    int t0 = max(0, wstart - W_F);

    int nf = 0, ns = 0;
    if (j < UNITS) {
        for (int i = 0; i < UNITS; ++i) {
            if (mask[i * UNITS + j] != 0.0f) {
                if (nf < CAP_R) {
                    size_t pi = ((size_t)v * UNITS + i) * UNITS + j;
                    int idx = j * CAP_R + nf;
                    float sg = sigma[pi], m = mu[pi];
                    rs_[idx] = i;
                    rw_[idx] = softplusf(w[pi]);
                    rc_[idx] = fast_exp2(sg * m * LOG2E);
                    rk_[idx] = -sg * LOG2E;
                    re_[idx] = erev[pi];
                }
                nf++;
            }
        }
        for (int s = 0; s < LEVELS; ++s) {
            if (sens_mask[s * UNITS + j] != 0.0f) {
                size_t pi = ((size_t)v * LEVELS + s) * UNITS + j;
                int idx = j * LEVELS + ns;
                float sg = sens_sigma[pi], m = sens_mu[pi];
                ss_[idx] = s;
                sw_[idx] = softplusf(sens_w[pi]);
                sc_[idx] = fast_exp2(sg * m * LOG2E);
                sk_[idx] = -sg * LOG2E;
                se_[idx] = sens_erev[pi];
                ns++;
            }
        }
    }
    cnts[j] = nf; scnts[j] = ns;
    __syncthreads();
    if (j == 0) {
        int mf = 0, ms = 0;
        for (int i = 0; i < UNITS; ++i) { mf = max(mf, cnts[i]); ms = max(ms, scnts[i]); }
        red[0] = mf; red[1] = ms;
    }
    __syncthreads();
    int maxF = red[0], maxS = red[1];

    int jc = (j < UNITS) ? j : (UNITS - 1);
    float cmt  = softplusf(cm[v * UNITS + jc]) * 6.0f;
    float gl   = softplusf(gleak[v * UNITS + jc]);
    float glvl = gl * vleak[v * UNITS + jc];
    float cgl  = cmt + gl + 1e-8f;
    float iw = (j < LEVELS) ? in_w[v * LEVELS + j]  : 0.0f;
    float ib = (j < LEVELS) ? in_b[v * LEVELS + j]  : 0.0f;
    float ow = (j < LEVELS) ? out_w[v * LEVELS + j] : 0.0f;
    float ob = (j < LEVELS) ? out_b[v * LEVELS + j] : 0.0f;

    if (maxF <= 11 && maxS <= 12)
        scan_loop_f<11, 12>(j, v, t0, wstart, tend, seq, rout, cmt, glvl, cgl, iw, ib, ow, ob, nf, ns,
                            rs_, rw_, rc_, rk_, re_, ss_, sw_, sc_, sk_, se_);
    else
        scan_loop_f<16, 17>(j, v, t0, wstart, tend, seq, rout, cmt, glvl, cgl, iw, ib, ow, ob, nf, ns,
                            rs_, rw_, rc_, rk_, re_, ss_, sw_, sc_, sk_, se_);
}

__global__ __launch_bounds__(256) void mlp_kernel(
    float* __restrict__ io,
    const float* __restrict__ tW1, const float* __restrict__ tb1,
    const float* __restrict__ tW2, const float* __restrict__ tb2,
    const float* __restrict__ tW3, const float* __restrict__ tb3,
    const float* __restrict__ gW1, const float* __restrict__ gb1,
    const float* __restrict__ gW2, const float* __restrict__ gb2,
    const float* __restrict__ gW3, const float* __restrict__ gb3)
{
    __shared__ __align__(16) float A[TROWS][272];
    __shared__ __align__(16) float Bf[TROWS][272];
    int base = blockIdx.x * TROWS;
    int tid = threadIdx.x;

    for (int e = tid; e < TROWS * DD; e += 256) {
        int r = e / DD, c = e % DD;
        A[r][c] = (base + r < TT) ? io[(size_t)(base + r) * DD + c] : 0.0f;
    }
    __syncthreads();
    for (int c = tid; c < 4 * LEVELS; c += 256) {
        int vv = c / LEVELS, cc = c % LEVELS;
        float acc[TROWS]; float bias = tb1[cc];
        #pragma unroll
        for (int r = 0; r < TROWS; ++r) acc[r] = bias;
        for (int k = 0; k < LEVELS; ++k) {
            float wv = tW1[k * LEVELS + cc];
            #pragma unroll
            for (int r = 0; r < TROWS; ++r) acc[r] = fmaf(A[r][vv * LEVELS + k], wv, acc[r]);
        }
        #pragma unroll
        for (int r = 0; r < TROWS; ++r) Bf[r][c] = sigf(acc[r]);
    }
    __syncthreads();
    for (int c = tid; c < 4 * 42; c += 256) {
        int vv = c / 42, cc = c % 42;
        float acc[TROWS]; float bias = tb2[cc];
        #pragma unroll
        for (int r = 0; r < TROWS; ++r) acc[r] = bias;
        for (int k = 0; k < LEVELS; ++k) {
            float wv = tW2[k * 42 + cc];
            #pragma unroll
            for (int r = 0; r < TROWS; ++r) acc[r] = fmaf(Bf[r][vv * LEVELS + k], wv, acc[r]);
        }
        #pragma unroll
        for (int r = 0; r < TROWS; ++r) A[r][vv * 42 + cc] = sigf(acc[r]);
    }
    __syncthreads();
    for (int c = tid; c < 4 * DD; c += 256) {
        int vv = c / DD, cc = c % DD;
        float acc[TROWS]; float bias = tb3[cc];
        #pragma unroll
        for (int r = 0; r < TROWS; ++r) acc[r] = bias;
        for (int k = 0; k < 42; ++k) {
            float wv = tW3[k * DD + cc];
            #pragma unroll
            for (int r = 0; r < TROWS; ++r) acc[r] = fmaf(A[r][vv * 42 + k], wv, acc[r]);
        }
        #pragma unroll
        for (int r = 0; r < TROWS; ++r) Bf[r][c] = sigf(acc[r]);
    }
    __syncthreads();
    for (int c = tid; c < 272; c += 256) {
        float acc[TROWS]; float bias = gb1[c];
        #pragma unroll
        for (int r = 0; r < TROWS; ++r) acc[r] = bias;
        for (int k = 0; k < 272; k += 4) {
            float w0 = gW1[(k + 0) * 272 + c];
            float w1 = gW1[(k + 1) * 272 + c];
            float w2 = gW1[(k + 2) * 272 + c];
            float w3 = gW1[(k + 3) * 272 + c];
            #pragma unroll
            for (int r = 0; r < TROWS; ++r) {
                float4 g4 = *reinterpret_cast<const float4*>(&Bf[r][k]);
                acc[r] = fmaf(g4.x, w0, fmaf(g4.y, w1, fmaf(g4.z, w2, fmaf(g4.w, w3, acc[r]))));
            }
        }
        #pragma unroll
        for (int r = 0; r < TROWS; ++r) A[r][c] = sigf(acc[r]);
    }
    __syncthreads();
    for (int c = tid; c < 170; c += 256) {
        float acc[TROWS]; float bias = gb2[c];
        #pragma unroll
        for (int r = 0; r < TROWS; ++r) acc[r] = bias;
        for (int k = 0; k < 272; k += 4) {
            float w0 = gW2[(k + 0) * 170 + c];
            float w1 = gW2[(k + 1) * 170 + c];
            float w2 = gW2[(k + 2) * 170 + c];
            float w3 = gW2[(k + 3) * 170 + c];
            #pragma unroll
            for (int r = 0; r < TROWS; ++r) {
                float4 g4 = *reinterpret_cast<const float4*>(&A[r][k]);
                acc[r] = fmaf(g4.x, w0, fmaf(g4.y, w1, fmaf(g4.z, w2, fmaf(g4.w, w3, acc[r]))));
            }
        }
        #pragma unroll
        for (int r = 0; r < TROWS; ++r) Bf[r][c] = sigf(acc[r]);
    }
    __syncthreads();
    for (int c = tid; c < DD; c += 256) {
        float acc[TROWS]; float bias = gb3[c];
        #pragma unroll
        for (int r = 0; r < TROWS; ++r) acc[r] = bias;
        for (int k = 0; k < 168; k += 4) {
            float w0 = gW3[(k + 0) * DD + c];
            float w1 = gW3[(k + 1) * DD + c];
            float w2 = gW3[(k + 2) * DD + c];
            float w3 = gW3[(k + 3) * DD + c];
            #pragma unroll
            for (int r = 0; r < TROWS; ++r) {
                float4 g4 = *reinterpret_cast<const float4*>(&Bf[r][k]);
                acc[r] = fmaf(g4.x, w0, fmaf(g4.y, w1, fmaf(g4.z, w2, fmaf(g4.w, w3, acc[r]))));
            }
        }
        for (int k = 168; k < 170; ++k) {
            float wv = gW3[k * DD + c];
            #pragma unroll
            for (int r = 0; r < TROWS; ++r) acc[r] = fmaf(Bf[r][k], wv, acc[r]);
        }
        #pragma unroll
        for (int r = 0; r < TROWS; ++r)
            if (base + r < TT) io[(size_t)(base + r) * DD + c] = acc[r];
    }
}

// ---------------------------------------------------------------------------
extern "C" void kernel_launch(void* const* d_in, const int* in_sizes, int n_in,
                              void* d_out, int out_size, void* d_ws, size_t ws_size,
                              hipStream_t stream)
{
    (void)in_sizes; (void)n_in; (void)out_size;
    const float* x        = (const float*)d_in[0];
    const float* pre_w1   = (const float*)d_in[1];
    const float* pre_b1   = (const float*)d_in[2];
    const float* pre_w2   = (const float*)d_in[3];
    const float* pre_b2   = (const float*)d_in[4];
    const float* gleak    = (const float*)d_in[5];
    const float* vleak    = (const float*)d_in[6];
    const float* cm       = (const float*)d_in[7];
    const float* w        = (const float*)d_in[8];
    const float* sigma    = (const float*)d_in[9];
    const float* mu       = (const float*)d_in[10];
    const float* erev     = (const float*)d_in[11];
    const float* sens_w   = (const float*)d_in[12];
    const float* sens_sig = (const float*)d_in[13];
    const float* sens_mu  = (const float*)d_in[14];
    const float* sens_er  = (const float*)d_in[15];
    const float* in_w     = (const float*)d_in[16];
    const float* in_b     = (const float*)d_in[17];
    const float* out_w    = (const float*)d_in[18];
    const float* out_b    = (const float*)d_in[19];
    const float* tW1      = (const float*)d_in[20];
    const float* tb1      = (const float*)d_in[21];
    const float* tW2      = (const float*)d_in[22];
    const float* tb2      = (const float*)d_in[23];
    const float* tW3      = (const float*)d_in[24];
    const float* tb3      = (const float*)d_in[25];
    const float* gW1      = (const float*)d_in[26];
    const float* gb1      = (const float*)d_in[27];
    const float* gW2      = (const float*)d_in[28];
    const float* gb2      = (const float*)d_in[29];
    const float* gW3      = (const float*)d_in[30];
    const float* gb3      = (const float*)d_in[31];
    const float* mask     = (const float*)d_in[32];
    const float* smask    = (const float*)d_in[33];

    float* out = (float*)d_out;

    size_t tab_bytes = (size_t)VARN * TT * UNITS * sizeof(float2);   // 53.5 MB
    size_t seq_bytes = (size_t)VARN * TT * LEVELS * sizeof(float);   // 8.9 MB
    size_t wts_bytes = (size_t)WTS_SHORTS * sizeof(unsigned short);  // 0.45 MB
    size_t ps_bytes  = (size_t)PSENS_N * sizeof(float4);             // 55 KB

    if (ws_size >= tab_bytes + seq_bytes + wts_bytes + ps_bytes) {
        float2* tab = (float2*)d_ws;
        float*  seq = (float*)((char*)d_ws + tab_bytes);
        unsigned short* wts = (unsigned short*)((char*)d_ws + tab_bytes + seq_bytes);
        float4* psens = (float4*)((char*)d_ws + tab_bytes + seq_bytes + wts_bytes);
        prep_all<<<dim3(306, 9), 256, 0, stream>>>(
            tW1, tW2, tW3, gW1, gW2, gW3, pre_w1, pre_w2,
            sens_w, sens_sig, sens_mu, sens_er, wts, psens);
        enc_mfma<<<EBLK, 256, 0, stream>>>(x, wts, pre_b1, pre_b2, seq);
        {
            int slabs = (TT + SENS_TPW - 1) / SENS_TPW;
            int waves = slabs * VARN;
            sens_kernel<<<(waves + 3) / 4, 256, 0, stream>>>(
                seq, psens, in_w, in_b, smask, tab);
        }
        scan_pre<<<NCHUNK, 256, 0, stream>>>(
            tab, gleak, vleak, cm, w, sigma, mu, erev, out_w, out_b, mask, out);
        mlp_mfma<<<MBLK, 256, 0, stream>>>(out, wts, tb1, tb2, tb3, gb1, gb2, gb3);
    } else if (ws_size >= seq_bytes) {
        float* seq = (float*)d_ws;
        enc_kernel<<<NB, 128, 0, stream>>>(x, pre_w1, pre_b1, pre_w2, pre_b2, seq);
        scan_fallback<<<VARN * NCHUNK_F, 64, 0, stream>>>(
            seq, gleak, vleak, cm, w, sigma, mu, erev,
            sens_w, sens_sig, sens_mu, sens_er,
            in_w, in_b, out_w, out_b, mask, smask, out);
        mlp_kernel<<<(TT + TROWS - 1) / TROWS, 256, 0, stream>>>(
            out, tW1, tb1, tW2, tb2, tW3, tb3, gW1, gb1, gW2, gb2, gW3, gb3);
    }
}